// Round 2
// baseline (1802.012 us; speedup 1.0000x reference)
//
#include <hip/hip_runtime.h>
#include <math.h>

typedef float f32x4 __attribute__((ext_vector_type(4)));
typedef __bf16 bf16x8 __attribute__((ext_vector_type(8)));
typedef __bf16 bf16x4 __attribute__((ext_vector_type(4)));

#define LRELU_ALPHA 0.2f

// ------------------------- CSR build -------------------------
__global__ void edge_count(const int* __restrict__ rows, int* __restrict__ cnt, int E) {
    int i = blockIdx.x * 256 + threadIdx.x;
    if (i < E) atomicAdd(&cnt[rows[i]], 1);
}

__global__ __launch_bounds__(512) void scan1(const int* __restrict__ in, int* __restrict__ out,
                                             int* __restrict__ bsum, int ncnt, int nout) {
    __shared__ int s[512];
    int t = threadIdx.x;
    int i = blockIdx.x * 512 + t;
    int v = (i < ncnt) ? in[i] : 0;
    s[t] = v; __syncthreads();
    for (int o = 1; o < 512; o <<= 1) {
        int u = (t >= o) ? s[t - o] : 0;
        __syncthreads();
        s[t] += u;
        __syncthreads();
    }
    if (i < nout) out[i] = s[t] - v;               // exclusive
    if (t == 511) bsum[blockIdx.x] = s[511];       // block total
}

__global__ void scan2(int* __restrict__ b, int nb) {   // single block, nb <= 256
    __shared__ int s[256];
    int t = threadIdx.x;
    int v = (t < nb) ? b[t] : 0;
    s[t] = v; __syncthreads();
    for (int o = 1; o < 256; o <<= 1) {
        int u = (t >= o) ? s[t - o] : 0;
        __syncthreads();
        s[t] += u;
        __syncthreads();
    }
    if (t < nb) b[t] = s[t] - v;                   // exclusive block offsets
}

__global__ __launch_bounds__(512) void scan3(int* __restrict__ out, const int* __restrict__ bsum, int nout) {
    int i = blockIdx.x * 512 + threadIdx.x;
    if (i < nout) out[i] += bsum[blockIdx.x];
}

__global__ void edge_fill(const int* __restrict__ rows, const int* __restrict__ cols,
                          const float* __restrict__ vals, int* __restrict__ cur,
                          int* __restrict__ ocol, float* __restrict__ oval, int E) {
    int i = blockIdx.x * 256 + threadIdx.x;
    if (i < E) {
        int r = rows[i];
        int p = atomicAdd(&cur[r], 1);
        ocol[p] = cols[i];
        oval[p] = vals[i];
    }
}

// ------------- weight transpose + bf16 hi/lo split (Dekker) -------------
__global__ void prep_wt(const float* __restrict__ W, unsigned short* __restrict__ Whi,
                        unsigned short* __restrict__ Wlo, int K) {
    int i = blockIdx.x * 256 + threadIdx.x;
    if (i < K * 128) {
        int k = i >> 7, n = i & 127;
        float f = W[i];
        __bf16 h = (__bf16)f;
        __bf16 l = (__bf16)(f - (float)h);
        Whi[n * K + k] = __builtin_bit_cast(unsigned short, h);
        Wlo[n * K + k] = __builtin_bit_cast(unsigned short, l);
    }
}

// ------------------------- SpMM + bias + LeakyReLU -------------------------
// one wave per output row; lane owns float2 at columns {2*lane, 2*lane+1}
__global__ __launch_bounds__(256) void spmm_lrelu(const int* __restrict__ ptr, const int* __restrict__ cols,
                                                  const float* __restrict__ vals, const float* __restrict__ x,
                                                  const float* __restrict__ bias, float* __restrict__ out,
                                                  int nrows) {
    int w = (blockIdx.x << 2) + (threadIdx.x >> 6);
    if (w >= nrows) return;
    int lane = threadIdx.x & 63;
    int s = ptr[w], e = ptr[w + 1];
    const float2* __restrict__ x2 = (const float2*)x;
    float ax = 0.f, ay = 0.f;
    int i = s;
    for (; i + 3 < e; i += 4) {
        int c0 = cols[i], c1 = cols[i + 1], c2 = cols[i + 2], c3 = cols[i + 3];
        float v0 = vals[i], v1 = vals[i + 1], v2 = vals[i + 2], v3 = vals[i + 3];
        float2 g0 = x2[(size_t)c0 * 64 + lane];
        float2 g1 = x2[(size_t)c1 * 64 + lane];
        float2 g2 = x2[(size_t)c2 * 64 + lane];
        float2 g3 = x2[(size_t)c3 * 64 + lane];
        ax += v0 * g0.x + v1 * g1.x + v2 * g2.x + v3 * g3.x;
        ay += v0 * g0.y + v1 * g1.y + v2 * g2.y + v3 * g3.y;
    }
    for (; i < e; i++) {
        int c = cols[i]; float v = vals[i];
        float2 g = x2[(size_t)c * 64 + lane];
        ax += v * g.x; ay += v * g.y;
    }
    float2 b2 = ((const float2*)bias)[lane];
    ax += b2.x; ay += b2.y;
    ax = ax >= 0.f ? ax : LRELU_ALPHA * ax;
    ay = ay >= 0.f ? ay : LRELU_ALPHA * ay;
    float2 o; o.x = ax; o.y = ay;
    ((float2*)out)[(size_t)w * 64 + lane] = o;
}

// ------------------------- MFMA GEMM, N = 128, split-bf16 (near-f32) -------------------------
// C[M,128] = A[M,K] @ W[K,128]. A f32 -> (hi,lo) bf16 on stage; W pre-split bf16 [128][K] hi/lo.
// acc += Ahi*Whi + Ahi*Wlo + Alo*Whi   (drops ~2^-18 Alo*Wlo term)
// KT = K/64 (2 or 4). KT==4: A = [A1 | A2] concat on K (128+128).
// EPI: 0 raw store, 1 +bias, 2 +bias then z = noise*exp(0.1+0.9*softplus(logstd)) + mean (logstd in-place in C)
template <int KT, int EPI>
__global__ __launch_bounds__(256) void gemm128(const float* __restrict__ A1, const float* __restrict__ A2,
                                               const unsigned short* __restrict__ Whi,
                                               const unsigned short* __restrict__ Wlo,
                                               const float* __restrict__ bias,
                                               const float* __restrict__ noise,
                                               float* C, int M) {
    constexpr int K = KT * 64;
    __shared__ __bf16 Ahi[128][72];   // +8 pad: row stride 144B (16B-aligned rows, 2-way banks only)
    __shared__ __bf16 Alo[128][72];
    __shared__ __bf16 Bhi[128][72];
    __shared__ __bf16 Blo[128][72];
    const int t = threadIdx.x;
    const int lane = t & 63;
    const int w = t >> 6;
    const int wr = w >> 1, wc = w & 1;
    const int l15 = lane & 15, l4 = lane >> 4;
    const int row0 = blockIdx.x * 128;

    f32x4 acc[4][4] = {};

    for (int k0 = 0; k0 < K; k0 += 64) {
        __syncthreads();
        {
            // stage A tile [128 rows][64 k] f32 -> bf16 hi/lo
            int r = t >> 1, half = t & 1;
            int rg = row0 + r;
            const float* src;
            if constexpr (KT == 2) {
                src = A1 + (size_t)rg * 128 + k0;
            } else {
                src = (k0 < 128) ? (A1 + (size_t)rg * 128 + k0)
                                 : (A2 + (size_t)rg * 128 + (k0 - 128));
            }
#pragma unroll
            for (int q = 0; q < 8; q++) {
                int kk = half * 32 + 4 * q;
                float4 f;
                if (rg < M) f = *(const float4*)(src + kk);
                else        f = make_float4(0.f, 0.f, 0.f, 0.f);
                bf16x4 h, l;
                h[0] = (__bf16)f.x; l[0] = (__bf16)(f.x - (float)h[0]);
                h[1] = (__bf16)f.y; l[1] = (__bf16)(f.y - (float)h[1]);
                h[2] = (__bf16)f.z; l[2] = (__bf16)(f.z - (float)h[2]);
                h[3] = (__bf16)f.w; l[3] = (__bf16)(f.w - (float)h[3]);
                *(bf16x4*)&Ahi[r][kk] = h;
                *(bf16x4*)&Alo[r][kk] = l;
            }
            // stage W tiles [128 cols][64 k] (already bf16 hi/lo, contiguous in k)
            int n = t >> 1;
            const unsigned short* whsrc = Whi + (size_t)n * K + k0 + half * 32;
            const unsigned short* wlsrc = Wlo + (size_t)n * K + k0 + half * 32;
#pragma unroll
            for (int q = 0; q < 4; q++) {
                uint4 uh = *(const uint4*)(whsrc + 8 * q);
                uint4 ul = *(const uint4*)(wlsrc + 8 * q);
                *(uint4*)&Bhi[n][half * 32 + 8 * q] = uh;
                *(uint4*)&Blo[n][half * 32 + 8 * q] = ul;
            }
        }
        __syncthreads();
#pragma unroll
        for (int kh = 0; kh < 2; kh++) {
            bf16x8 ah[4], al[4], bh[4], bl[4];
#pragma unroll
            for (int mr = 0; mr < 4; mr++) {
                ah[mr] = *(const bf16x8*)&Ahi[wr * 64 + mr * 16 + l15][kh * 32 + l4 * 8];
                al[mr] = *(const bf16x8*)&Alo[wr * 64 + mr * 16 + l15][kh * 32 + l4 * 8];
            }
#pragma unroll
            for (int nc = 0; nc < 4; nc++) {
                bh[nc] = *(const bf16x8*)&Bhi[wc * 64 + nc * 16 + l15][kh * 32 + l4 * 8];
                bl[nc] = *(const bf16x8*)&Blo[wc * 64 + nc * 16 + l15][kh * 32 + l4 * 8];
            }
#pragma unroll
            for (int mr = 0; mr < 4; mr++)
#pragma unroll
                for (int nc = 0; nc < 4; nc++) {
                    acc[mr][nc] = __builtin_amdgcn_mfma_f32_16x16x32_bf16(ah[mr], bh[nc], acc[mr][nc], 0, 0, 0);
                    acc[mr][nc] = __builtin_amdgcn_mfma_f32_16x16x32_bf16(ah[mr], bl[nc], acc[mr][nc], 0, 0, 0);
                    acc[mr][nc] = __builtin_amdgcn_mfma_f32_16x16x32_bf16(al[mr], bh[nc], acc[mr][nc], 0, 0, 0);
                }
        }
    }

    // epilogue: C/D layout col = lane&15, row = (lane>>4)*4 + reg
#pragma unroll
    for (int mr = 0; mr < 4; mr++) {
        int rowb = row0 + wr * 64 + mr * 16 + l4 * 4;
#pragma unroll
        for (int nc = 0; nc < 4; nc++) {
            int col = wc * 64 + nc * 16 + l15;
#pragma unroll
            for (int j = 0; j < 4; j++) {
                int r = rowb + j;
                if (r < M) {
                    float v = acc[mr][nc][j];
                    if constexpr (EPI == 0) {
                        C[(size_t)r * 128 + col] = v;
                    } else if constexpr (EPI == 1) {
                        C[(size_t)r * 128 + col] = v + bias[col];
                    } else {
                        float mean = v + bias[col];
                        float ls = C[(size_t)r * 128 + col];
                        float sp = ls > 0.f ? ls + log1pf(expf(-ls)) : log1pf(expf(ls));
                        float sg = expf(0.1f + 0.9f * sp);
                        C[(size_t)r * 128 + col] = noise[(size_t)r * 128 + col] * sg + mean;
                    }
                }
            }
        }
    }
}

// ------------------------- launcher -------------------------
extern "C" void kernel_launch(void* const* d_in, const int* in_sizes, int n_in,
                              void* d_out, int out_size, void* d_ws, size_t ws_size,
                              hipStream_t stream) {
    const float* ufea    = (const float*)d_in[0];
    const float* vfea    = (const float*)d_in[1];
    const int*   uv_rows = (const int*)d_in[2];
    const int*   uv_cols = (const int*)d_in[3];
    const float* uv_vals = (const float*)d_in[4];
    const int*   vu_rows = (const int*)d_in[5];
    const int*   vu_cols = (const int*)d_in[6];
    const float* vu_vals = (const float*)d_in[7];
    const float* noise_u = (const float*)d_in[8];
    const float* noise_v = (const float*)d_in[9];
    const float* gc1_W  = (const float*)d_in[10];
    const float* gc1_b  = (const float*)d_in[11];
    const float* gc3m_W = (const float*)d_in[12];
    const float* gc3m_b = (const float*)d_in[13];
    const float* gc3s_W = (const float*)d_in[14];
    const float* gc3s_b = (const float*)d_in[15];
    const float* um_W = (const float*)d_in[16];
    const float* um_b = (const float*)d_in[17];
    const float* us_W = (const float*)d_in[18];
    const float* us_b = (const float*)d_in[19];
    const float* im_W = (const float*)d_in[20];
    const float* im_b = (const float*)d_in[21];
    const float* is_W = (const float*)d_in[22];
    const float* is_b = (const float*)d_in[23];

    const int H  = in_sizes[11];          // 128
    const int D  = in_sizes[10] / H;      // 128
    const int NU = in_sizes[0] / D;       // 100000
    const int NV = in_sizes[1] / D;       // 50000
    const int E  = in_sizes[2];           // 1600000

    // workspace layout
    char* ws = (char*)d_ws;
    size_t off = 0;
    auto alloc = [&](size_t bytes) -> char* {
        char* p = ws + off;
        off = (off + bytes + 255) & ~(size_t)255;
        return p;
    };
    unsigned short* wt_gc1_h  = (unsigned short*)alloc(128 * 128 * 2);
    unsigned short* wt_gc1_l  = (unsigned short*)alloc(128 * 128 * 2);
    unsigned short* wt_gc3m_h = (unsigned short*)alloc(128 * 128 * 2);
    unsigned short* wt_gc3m_l = (unsigned short*)alloc(128 * 128 * 2);
    unsigned short* wt_gc3s_h = (unsigned short*)alloc(128 * 128 * 2);
    unsigned short* wt_gc3s_l = (unsigned short*)alloc(128 * 128 * 2);
    unsigned short* wt_um_h = (unsigned short*)alloc(128 * 256 * 2);
    unsigned short* wt_um_l = (unsigned short*)alloc(128 * 256 * 2);
    unsigned short* wt_us_h = (unsigned short*)alloc(128 * 256 * 2);
    unsigned short* wt_us_l = (unsigned short*)alloc(128 * 256 * 2);
    unsigned short* wt_im_h = (unsigned short*)alloc(128 * 256 * 2);
    unsigned short* wt_im_l = (unsigned short*)alloc(128 * 256 * 2);
    unsigned short* wt_is_h = (unsigned short*)alloc(128 * 256 * 2);
    unsigned short* wt_is_l = (unsigned short*)alloc(128 * 256 * 2);
    int*   ptr_uv = (int*)alloc((size_t)(NU + 1) * 4);
    int*   cur_uv = (int*)alloc((size_t)NU * 4);
    int*   col_uv = (int*)alloc((size_t)E * 4);
    float* val_uv = (float*)alloc((size_t)E * 4);
    int*   ptr_vu = (int*)alloc((size_t)(NV + 1) * 4);
    int*   cur_vu = (int*)alloc((size_t)NV * 4);
    int*   col_vu = (int*)alloc((size_t)E * 4);
    float* val_vu = (float*)alloc((size_t)E * 4);
    int*   bsum   = (int*)alloc(1024 * 4);
    float* bufA = (float*)alloc((size_t)NU * 128 * 4);
    float* bufB = (float*)alloc((size_t)NU * 128 * 4);

    float* outU = (float*)d_out;
    float* outI = outU + (size_t)NU * H;

    const int eb = (E + 255) / 256;
    const int nbU = (NU + 1 + 511) / 512;
    const int nbV = (NV + 1 + 511) / 512;
    const int gU = (NU + 127) / 128, gV = (NV + 127) / 128;
    const int sU = (NU + 3) / 4, sV = (NV + 3) / 4;

    // ---- CSR build (both adjacencies) ----
    hipMemsetAsync(cur_uv, 0, (size_t)NU * 4, stream);
    hipMemsetAsync(cur_vu, 0, (size_t)NV * 4, stream);
    edge_count<<<eb, 256, 0, stream>>>(uv_rows, cur_uv, E);
    edge_count<<<eb, 256, 0, stream>>>(vu_rows, cur_vu, E);
    scan1<<<nbU, 512, 0, stream>>>(cur_uv, ptr_uv, bsum, NU, NU + 1);
    scan2<<<1, 256, 0, stream>>>(bsum, nbU);
    scan3<<<nbU, 512, 0, stream>>>(ptr_uv, bsum, NU + 1);
    scan1<<<nbV, 512, 0, stream>>>(cur_vu, ptr_vu, bsum, NV, NV + 1);
    scan2<<<1, 256, 0, stream>>>(bsum, nbV);
    scan3<<<nbV, 512, 0, stream>>>(ptr_vu, bsum, NV + 1);
    hipMemcpyAsync(cur_uv, ptr_uv, (size_t)NU * 4, hipMemcpyDeviceToDevice, stream);
    hipMemcpyAsync(cur_vu, ptr_vu, (size_t)NV * 4, hipMemcpyDeviceToDevice, stream);
    edge_fill<<<eb, 256, 0, stream>>>(uv_rows, uv_cols, uv_vals, cur_uv, col_uv, val_uv, E);
    edge_fill<<<eb, 256, 0, stream>>>(vu_rows, vu_cols, vu_vals, cur_vu, col_vu, val_vu, E);

    // ---- weights: transpose + bf16 hi/lo split ----
    prep_wt<<<64, 256, 0, stream>>>(gc1_W, wt_gc1_h, wt_gc1_l, 128);
    prep_wt<<<64, 256, 0, stream>>>(gc3m_W, wt_gc3m_h, wt_gc3m_l, 128);
    prep_wt<<<64, 256, 0, stream>>>(gc3s_W, wt_gc3s_h, wt_gc3s_l, 128);
    prep_wt<<<128, 256, 0, stream>>>(um_W, wt_um_h, wt_um_l, 256);
    prep_wt<<<128, 256, 0, stream>>>(us_W, wt_us_h, wt_us_l, 256);
    prep_wt<<<128, 256, 0, stream>>>(im_W, wt_im_h, wt_im_l, 256);
    prep_wt<<<128, 256, 0, stream>>>(is_W, wt_is_h, wt_is_l, 256);

    // ---- user path ----
    gemm128<2, 0><<<gU, 256, 0, stream>>>(ufea, nullptr, wt_gc1_h, wt_gc1_l, nullptr, nullptr, bufA, NU);
    spmm_lrelu<<<sV, 256, 0, stream>>>(ptr_vu, col_vu, val_vu, bufA, gc1_b, bufB, NV);          // user_ho [NV]
    gemm128<2, 0><<<gV, 256, 0, stream>>>(bufB, nullptr, wt_gc3s_h, wt_gc3s_l, nullptr, nullptr, bufA, NV);
    spmm_lrelu<<<sU, 256, 0, stream>>>(ptr_uv, col_uv, val_uv, bufA, gc3s_b, outU, NU);         // uhl -> d_out
    gemm128<4, 1><<<gU, 256, 0, stream>>>(outU, ufea, wt_us_h, wt_us_l, us_b, nullptr, outU, NU);   // user_logstd
    gemm128<2, 0><<<gV, 256, 0, stream>>>(bufB, nullptr, wt_gc3m_h, wt_gc3m_l, nullptr, nullptr, bufA, NV);
    spmm_lrelu<<<sU, 256, 0, stream>>>(ptr_uv, col_uv, val_uv, bufA, gc3m_b, bufB, NU);         // uhm [NU]
    gemm128<4, 2><<<gU, 256, 0, stream>>>(bufB, ufea, wt_um_h, wt_um_l, um_b, noise_u, outU, NU);   // user_z

    // ---- item path ----
    gemm128<2, 0><<<gV, 256, 0, stream>>>(vfea, nullptr, wt_gc1_h, wt_gc1_l, nullptr, nullptr, bufA, NV);
    spmm_lrelu<<<sU, 256, 0, stream>>>(ptr_uv, col_uv, val_uv, bufA, gc1_b, bufB, NU);          // item_ho [NU]
    gemm128<2, 0><<<gU, 256, 0, stream>>>(bufB, nullptr, wt_gc3s_h, wt_gc3s_l, nullptr, nullptr, bufA, NU);
    spmm_lrelu<<<sV, 256, 0, stream>>>(ptr_vu, col_vu, val_vu, bufA, gc3s_b, outI, NV);         // ihl -> d_out
    gemm128<4, 1><<<gV, 256, 0, stream>>>(outI, vfea, wt_is_h, wt_is_l, is_b, nullptr, outI, NV);   // item_logstd
    gemm128<2, 0><<<gU, 256, 0, stream>>>(bufB, nullptr, wt_gc3m_h, wt_gc3m_l, nullptr, nullptr, bufA, NU);
    spmm_lrelu<<<sV, 256, 0, stream>>>(ptr_vu, col_vu, val_vu, bufA, gc3m_b, bufB, NV);         // ihm [NV]
    gemm128<4, 2><<<gV, 256, 0, stream>>>(bufB, vfea, wt_im_h, wt_im_l, im_b, noise_v, outI, NV);   // item_z

    (void)n_in; (void)out_size; (void)ws_size;
}